// Round 28
// baseline (883.516 us; speedup 1.0000x reference)
//
#include <hip/hip_runtime.h>
#include <hip/hip_bf16.h>

#define DD 128
#define CAP02 16
#define CAP1 32
#define OVFC 4096

typedef float f32x4 __attribute__((ext_vector_type(4)));
typedef __bf16 bf16x8 __attribute__((ext_vector_type(8)));

static __device__ __forceinline__ void wave_lds_fence() {
    asm volatile("s_waitcnt lgkmcnt(0)" ::: "memory");
    __builtin_amdgcn_sched_barrier(0);
}

// ---- prep: softmax + premultiplied bf16 W^T tables [outcol][k] ----
__global__ void prep_kernel(const float* __restrict__ Wl0, const float* __restrict__ bl0, const float* __restrict__ Wr0,
                            const float* __restrict__ Wl1, const float* __restrict__ bl1, const float* __restrict__ Wr1,
                            const float* __restrict__ Wl2, const float* __restrict__ bl2, const float* __restrict__ Wr2,
                            const float* __restrict__ rl,
                            __bf16* __restrict__ WtA, __bf16* __restrict__ Wtb,
                            float* __restrict__ ba, float* __restrict__ bb,
                            float* __restrict__ rw_out) {
    const int n = threadIdx.x;
    float l0 = rl[0], l1 = rl[1], l2 = rl[2];
    float mx = fmaxf(l0, fmaxf(l1, l2));
    float e0 = expf(l0 - mx), e1 = expf(l1 - mx), e2 = expf(l2 - mx);
    float s = e0 + e1 + e2;
    float r0 = e0 / s, r1 = e1 / s, r2 = e2 / s;
    for (int k = 0; k < DD; k++) {
        WtA[n * 384 + k]       = (__bf16)(r0 * Wl0[k * DD + n]);
        WtA[n * 384 + 128 + k] = (__bf16)(r0 * Wr0[k * DD + n] + r2 * Wr2[k * DD + n]);
        WtA[n * 384 + 256 + k] = (__bf16)(r2 * Wl2[k * DD + n]);
        Wtb[n * 256 + k]       = (__bf16)(r1 * Wl1[k * DD + n]);
        Wtb[n * 256 + 128 + k] = (__bf16)(r1 * Wr1[k * DD + n]);
    }
    ba[n] = r0 * bl0[n] + r2 * bl2[n];
    bb[n] = r1 * bl1[n];
    if (n < 3) rw_out[n] = (n == 0 ? r0 : (n == 1 ? r1 : r2));
}

// ---- fill: bucket[d][slot]=src; cnt[d]=true degree; overflow list ----
__global__ __launch_bounds__(256) void fill_bucket(const int* __restrict__ src, const int* __restrict__ dst,
                                                   int E, int Nd, int Ns, int cap,
                                                   int* __restrict__ cnt, int* __restrict__ bucket,
                                                   int* __restrict__ ovf_cnt, int2* __restrict__ ovf) {
    int e = blockIdx.x * 256 + threadIdx.x;
    if (e >= E) return;
    int d = dst[e];
    if (d < 0 || d >= Nd) return;
    int s = src[e];
    if (s < 0 || s >= Ns) return;
    int slot = atomicAdd(&cnt[d], 1);
    if (slot < cap) bucket[(size_t)d * cap + slot] = s;
    else { int o = atomicAdd(ovf_cnt, 1); if (o < OVFC) ovf[o] = make_int2(d, s); }
}

// ---- fused gather + MFMA: 4 INDEPENDENT waves/block, private LDS per wave,
//      wave-local lgkmcnt fences (no s_barrier), slot-major gather ----
template <int KSRC>
__global__ __launch_bounds__(256) void fused_tile(const float* __restrict__ XA,
                                                  const float* __restrict__ XB,
                                                  const float* __restrict__ XR,
                                                  const int* __restrict__ C0, const int* __restrict__ BK0, int cap0,
                                                  const int* __restrict__ C2, const int* __restrict__ BK2, int cap2,
                                                  const __bf16* __restrict__ Wt,
                                                  const float* __restrict__ bias,
                                                  float* __restrict__ out, int Nrows) {
    constexpr int K = KSRC * 128;
    constexpr int KP = 136;                       // 128 + 8 pad: 2-way-free banks
    __shared__ __bf16 A[4][16 * KP];              // private per wave; 17408 B/block
    const int w = threadIdx.x >> 6;
    const int lane = threadIdx.x & 63;
    __bf16* Aw = A[w];
    const int t = blockIdx.x * 4 + w;
    if (t * 16 >= Nrows) return;                  // no barriers -> safe early exit
    const int c2 = lane * 2;
    const int m = lane & 15, g = lane >> 4;

    f32x4 acc[8];
#pragma unroll
    for (int n = 0; n < 8; n++) acc[n] = (f32x4)0.0f;

#pragma unroll
    for (int sec = 0; sec < KSRC; sec++) {
        if (sec == 1) {                           // ---- x section ----
#pragma unroll
            for (int r = 0; r < 16; r++) {
                const int row = t * 16 + r;
                float2 v = make_float2(0.f, 0.f);
                if (row < Nrows) v = ((const float2*)(XR + (size_t)row * DD))[lane];
                Aw[r * KP + c2] = (__bf16)v.x;
                Aw[r * KP + c2 + 1] = (__bf16)v.y;
            }
        } else {                                  // ---- mean section (slot-major MLP) ----
            const int* cnt = (sec == 0) ? C0 : C2;
            const int* bkp = (sec == 0) ? BK0 : BK2;
            const int cap  = (sec == 0) ? cap0 : cap2;
            const float* X = (sec == 0) ? XA : XB;
            int du[16];
            float ax[16], ay[16];
            int mdu = 0;
#pragma unroll
            for (int r = 0; r < 16; r++) {
                const int row = t * 16 + r;
                int d = (row < Nrows) ? cnt[row] : 0;
                du[r] = d < cap ? d : cap;
                if (du[r] > mdu) mdu = du[r];
                ax[r] = 0.f; ay[r] = 0.f;
            }
            for (int i = 0; i < mdu; i++) {       // wave-uniform trip/branches
#pragma unroll
                for (int r = 0; r < 16; r++) {
                    if (i < du[r]) {
                        const int s = bkp[(size_t)(t * 16 + r) * cap + i];
                        const float2 v = ((const float2*)(X + (size_t)s * DD))[lane];
                        ax[r] += v.x; ay[r] += v.y;
                    }
                }
            }
#pragma unroll
            for (int r = 0; r < 16; r++) {
                const int row = t * 16 + r;
                const float sc = (row < Nrows) ? 1.0f / fmaxf((float)cnt[row], 1.0f) : 0.f;
                Aw[r * KP + c2] = (__bf16)(ax[r] * sc);
                Aw[r * KP + c2 + 1] = (__bf16)(ay[r] * sc);
            }
        }
        wave_lds_fence();                         // own-wave ds_writes visible
#pragma unroll
        for (int ks = 0; ks < 4; ks++) {
            const int koff = ks * 32 + g * 8;
            const bf16x8 a = *(const bf16x8*)(&Aw[m * KP + koff]);
#pragma unroll
            for (int n = 0; n < 8; n++) {
                const bf16x8 b = *(const bf16x8*)(Wt + (size_t)(n * 16 + m) * K + sec * 128 + koff);
                acc[n] = __builtin_amdgcn_mfma_f32_16x16x32_bf16(a, b, acc[n], 0, 0, 0);
            }
        }
        wave_lds_fence();                         // own-wave ds_reads drained before overwrite
    }

#pragma unroll
    for (int n = 0; n < 8; n++) {
        const int col = n * 16 + m;
        const float bv = bias[col];
#pragma unroll
        for (int r = 0; r < 4; r++) {
            const int orow = t * 16 + g * 4 + r;
            if (orow < Nrows) out[(size_t)orow * DD + col] = acc[n][r] + bv;
        }
    }
}

// ---- exact overflow correction (rare) ----
__global__ __launch_bounds__(128) void ovf_fix(const int* __restrict__ ovfc, const int2* __restrict__ ovf,
                                               const float* __restrict__ x, const int* __restrict__ cnt,
                                               const __bf16* __restrict__ Wt, int K, int sec,
                                               float* __restrict__ out) {
    int m = *ovfc;
    if (m > OVFC) m = OVFC;
    const int n = threadIdx.x;
    for (int i = blockIdx.x; i < m; i += gridDim.x) {
        const int2 p = ovf[i];
        const float sc = 1.0f / fmaxf((float)cnt[p.x], 1.0f);
        float acc = 0.f;
        for (int k = 0; k < DD; k++)
            acc += x[(size_t)p.y * DD + k] * (float)Wt[(size_t)n * K + sec + k];
        atomicAdd(&out[(size_t)p.x * DD + n], acc * sc);
    }
}

extern "C" void kernel_launch(void* const* d_in, const int* in_sizes, int n_in,
                              void* d_out, int out_size, void* d_ws, size_t ws_size,
                              hipStream_t stream) {
    if (n_in != 18) return;

    const float* x_a = (const float*)d_in[0];
    const float* x_b = (const float*)d_in[1];
    const int* e0_src = (const int*)d_in[2];
    const int* e0_dst = (const int*)d_in[3];
    const int* e1_src = (const int*)d_in[4];
    const int* e1_dst = (const int*)d_in[5];
    const int* e2_src = (const int*)d_in[6];
    const int* e2_dst = (const int*)d_in[7];
    const float* Wl0 = (const float*)d_in[8];
    const float* bl0 = (const float*)d_in[9];
    const float* Wr0 = (const float*)d_in[10];
    const float* Wl1 = (const float*)d_in[11];
    const float* bl1 = (const float*)d_in[12];
    const float* Wr1 = (const float*)d_in[13];
    const float* Wl2 = (const float*)d_in[14];
    const float* bl2 = (const float*)d_in[15];
    const float* Wr2 = (const float*)d_in[16];
    const float* rl  = (const float*)d_in[17];

    const int Na = in_sizes[0] / DD;   // 200000
    const int Nb = in_sizes[1] / DD;   // 100000
    const int E0 = in_sizes[2], E1 = in_sizes[4], E2 = in_sizes[6];

    float* out_f = (float*)d_out;
    float* out_a = out_f;
    float* out_b = out_f + (size_t)Na * DD;
    float* rw_out = out_f + (size_t)Na * DD + (size_t)Nb * DD;

    char* base = (char*)d_ws;
    size_t off = 0;
    auto alloc = [&](size_t bytes) { char* r = base + off; off += (bytes + 511) & ~(size_t)511; return r; };
    int* cnt0 = (int*)alloc((size_t)Na * 4);
    int* cnt1 = (int*)alloc((size_t)Nb * 4);
    int* cnt2 = (int*)alloc((size_t)Na * 4);
    int* ovfc = (int*)alloc(512);
    int2* ovf0 = (int2*)alloc(OVFC * 8);
    int2* ovf1 = (int2*)alloc(OVFC * 8);
    int2* ovf2 = (int2*)alloc(OVFC * 8);
    size_t zero_hi = off;
    __bf16* WtA = (__bf16*)alloc(128 * 384 * 2);
    __bf16* Wtb = (__bf16*)alloc(128 * 256 * 2);
    float* ba = (float*)alloc(512);
    float* bb = (float*)alloc(512);
    size_t b0cap = (size_t)Na * CAP02;
    size_t b1cap = (size_t)Nb * CAP1;
    int* bucket0 = (int*)alloc((b0cap > b1cap ? b0cap : b1cap) * 4);
    int* bucket2 = (int*)alloc((size_t)Na * CAP02 * 4);
    int* bucket1 = bucket0;                     // reused after out_b completes
    if (ws_size < off) return;                  // proven adequate (R24-R27 ran)

    hipMemsetAsync(d_ws, 0, zero_hi, stream);
    prep_kernel<<<1, 128, 0, stream>>>(Wl0, bl0, Wr0, Wl1, bl1, Wr1, Wl2, bl2, Wr2, rl,
                                       WtA, Wtb, ba, bb, rw_out);

    const int fb0 = (E0 + 255) / 256, fb1 = (E1 + 255) / 256, fb2 = (E2 + 255) / 256;

    // ---- out_b: relation 1 (a -> b) ----
    fill_bucket<<<fb1, 256, 0, stream>>>(e1_src, e1_dst, E1, Nb, Na, CAP1, cnt1, bucket1, ovfc + 1, ovf1);
    fused_tile<2><<<(Nb + 63) / 64, 256, 0, stream>>>(x_a, nullptr, x_b,
                                                      cnt1, bucket1, CAP1,
                                                      nullptr, nullptr, 0,
                                                      Wtb, bb, out_b, Nb);
    ovf_fix<<<32, 128, 0, stream>>>(ovfc + 1, ovf1, x_a, cnt1, Wtb, 256, 0, out_b);

    // ---- out_a: relations 0 (a->a) + 2 (b->a) ----
    fill_bucket<<<fb0, 256, 0, stream>>>(e0_src, e0_dst, E0, Na, Na, CAP02, cnt0, bucket0, ovfc + 0, ovf0);
    fill_bucket<<<fb2, 256, 0, stream>>>(e2_src, e2_dst, E2, Na, Nb, CAP02, cnt2, bucket2, ovfc + 2, ovf2);
    fused_tile<3><<<(Na + 63) / 64, 256, 0, stream>>>(x_a, x_b, x_a,
                                                      cnt0, bucket0, CAP02,
                                                      cnt2, bucket2, CAP02,
                                                      WtA, ba, out_a, Na);
    ovf_fix<<<32, 128, 0, stream>>>(ovfc + 0, ovf0, x_a, cnt0, WtA, 384, 0, out_a);
    ovf_fix<<<32, 128, 0, stream>>>(ovfc + 2, ovf2, x_b, cnt2, WtA, 384, 256, out_a);
}

// Round 29
// 560.971 us; speedup vs baseline: 1.5750x; 1.5750x over previous
//
#include <hip/hip_runtime.h>
#include <hip/hip_bf16.h>

#define DD 128
#define CAP02 16
#define CAP1 32
#define OVFC 4096

typedef float f32x4 __attribute__((ext_vector_type(4)));
typedef __bf16 bf16x8 __attribute__((ext_vector_type(8)));

// ---- prep: softmax + premultiplied bf16 W^T tables [outcol][k] ----
__global__ void prep_kernel(const float* __restrict__ Wl0, const float* __restrict__ bl0, const float* __restrict__ Wr0,
                            const float* __restrict__ Wl1, const float* __restrict__ bl1, const float* __restrict__ Wr1,
                            const float* __restrict__ Wl2, const float* __restrict__ bl2, const float* __restrict__ Wr2,
                            const float* __restrict__ rl,
                            __bf16* __restrict__ WtA, __bf16* __restrict__ Wtb,
                            float* __restrict__ ba, float* __restrict__ bb,
                            float* __restrict__ rw_out) {
    const int n = threadIdx.x;
    float l0 = rl[0], l1 = rl[1], l2 = rl[2];
    float mx = fmaxf(l0, fmaxf(l1, l2));
    float e0 = expf(l0 - mx), e1 = expf(l1 - mx), e2 = expf(l2 - mx);
    float s = e0 + e1 + e2;
    float r0 = e0 / s, r1 = e1 / s, r2 = e2 / s;
    for (int k = 0; k < DD; k++) {
        WtA[n * 384 + k]       = (__bf16)(r0 * Wl0[k * DD + n]);
        WtA[n * 384 + 128 + k] = (__bf16)(r0 * Wr0[k * DD + n] + r2 * Wr2[k * DD + n]);
        WtA[n * 384 + 256 + k] = (__bf16)(r2 * Wl2[k * DD + n]);
        Wtb[n * 256 + k]       = (__bf16)(r1 * Wl1[k * DD + n]);
        Wtb[n * 256 + 128 + k] = (__bf16)(r1 * Wr1[k * DD + n]);
    }
    ba[n] = r0 * bl0[n] + r2 * bl2[n];
    bb[n] = r1 * bl1[n];
    if (n < 3) rw_out[n] = (n == 0 ? r0 : (n == 1 ? r1 : r2));
}

// ---- fill: bucket[d][slot]=src; cnt[d]=true degree; overflow list ----
__global__ __launch_bounds__(256) void fill_bucket(const int* __restrict__ src, const int* __restrict__ dst,
                                                   int E, int Nd, int Ns, int cap,
                                                   int* __restrict__ cnt, int* __restrict__ bucket,
                                                   int* __restrict__ ovf_cnt, int2* __restrict__ ovf) {
    int e = blockIdx.x * 256 + threadIdx.x;
    if (e >= E) return;
    int d = dst[e];
    if (d < 0 || d >= Nd) return;
    int s = src[e];
    if (s < 0 || s >= Ns) return;
    int slot = atomicAdd(&cnt[d], 1);
    if (slot < cap) bucket[(size_t)d * cap + slot] = s;
    else { int o = atomicAdd(ovf_cnt, 1); if (o < OVFC) ovf[o] = make_int2(d, s); }
}

// ---- fused gather + MFMA: 1 wave / 16-row tile.
//      SINGLE gather phase: both mean sections slot-major into regs (concurrent),
//      x section read direct-from-global during MFMA. One __syncthreads total. ----
template <int KSRC>
__global__ __launch_bounds__(64, 3) void fused_tile(const float* __restrict__ XA,
                                                    const float* __restrict__ XB,
                                                    const float* __restrict__ XR,
                                                    const int* __restrict__ C0, const int* __restrict__ BK0, int cap0,
                                                    const int* __restrict__ C2, const int* __restrict__ BK2, int cap2,
                                                    const __bf16* __restrict__ Wt,
                                                    const float* __restrict__ bias,
                                                    float* __restrict__ out, int Nrows) {
    constexpr int K = KSRC * 128;
    constexpr int NMEAN = KSRC - 1;               // 2 mean sections for out_a, 1 for out_b
    constexpr int KP = 136;                       // 128 + 8 pad: 2-way-free banks
    __shared__ __bf16 A[NMEAN][16 * KP];          // 8704B (KSRC=3) / 4352B (KSRC=2)
    const int lane = threadIdx.x;
    const int t = blockIdx.x;
    const int c2 = lane * 2;
    const int m = lane & 15, g = lane >> 4;

    // ---- gather BOTH mean sections concurrently (slot-major, regs) ----
    {
        int du0[16];
        float a0x[16], a0y[16];
        int mdu0 = 0;
#pragma unroll
        for (int r = 0; r < 16; r++) {
            const int row = t * 16 + r;
            int d = (row < Nrows) ? C0[row] : 0;
            du0[r] = d < cap0 ? d : cap0;
            if (du0[r] > mdu0) mdu0 = du0[r];
            a0x[r] = 0.f; a0y[r] = 0.f;
        }
        int du2[16];
        float a2x[16], a2y[16];
        int mdu2 = 0;
        if (NMEAN == 2) {
#pragma unroll
            for (int r = 0; r < 16; r++) {
                const int row = t * 16 + r;
                int d = (row < Nrows) ? C2[row] : 0;
                du2[r] = d < cap2 ? d : cap2;
                if (du2[r] > mdu2) mdu2 = du2[r];
                a2x[r] = 0.f; a2y[r] = 0.f;
            }
        }
        // independent loops -> compiler interleaves; ~all loads in flight
        for (int i = 0; i < mdu0; i++) {
#pragma unroll
            for (int r = 0; r < 16; r++) {
                if (i < du0[r]) {
                    const int s = BK0[(size_t)(t * 16 + r) * cap0 + i];
                    const float2 v = ((const float2*)(XA + (size_t)s * DD))[lane];
                    a0x[r] += v.x; a0y[r] += v.y;
                }
            }
        }
        if (NMEAN == 2) {
            for (int i = 0; i < mdu2; i++) {
#pragma unroll
                for (int r = 0; r < 16; r++) {
                    if (i < du2[r]) {
                        const int s = BK2[(size_t)(t * 16 + r) * cap2 + i];
                        const float2 v = ((const float2*)(XB + (size_t)s * DD))[lane];
                        a2x[r] += v.x; a2y[r] += v.y;
                    }
                }
            }
        }
#pragma unroll
        for (int r = 0; r < 16; r++) {
            const int row = t * 16 + r;
            const float sc0 = (row < Nrows) ? 1.0f / fmaxf((float)C0[row], 1.0f) : 0.f;
            A[0][r * KP + c2] = (__bf16)(a0x[r] * sc0);
            A[0][r * KP + c2 + 1] = (__bf16)(a0y[r] * sc0);
            if (NMEAN == 2) {
                const float sc2 = (row < Nrows) ? 1.0f / fmaxf((float)C2[row], 1.0f) : 0.f;
                A[1][r * KP + c2] = (__bf16)(a2x[r] * sc2);
                A[1][r * KP + c2 + 1] = (__bf16)(a2y[r] * sc2);
            }
        }
    }
    __syncthreads();                              // single fence (1-wave block)

    // ---- MFMA: sec0 (LDS), sec1 = x (direct global), sec2 (LDS) ----
    const int xrow = t * 16 + m;
    const float* xp = XR + (size_t)(xrow < Nrows ? xrow : 0) * DD;
    f32x4 acc[8];
#pragma unroll
    for (int n = 0; n < 8; n++) acc[n] = (f32x4)0.0f;

#pragma unroll
    for (int sec = 0; sec < KSRC; sec++) {
#pragma unroll
        for (int ks = 0; ks < 4; ks++) {
            const int koff = ks * 32 + g * 8;
            bf16x8 a;
            if (sec == 1) {                       // x: 8 contiguous f32 from own row
                const float4 v0 = ((const float4*)(xp + koff))[0];
                const float4 v1 = ((const float4*)(xp + koff))[1];
                a[0] = (__bf16)v0.x; a[1] = (__bf16)v0.y;
                a[2] = (__bf16)v0.z; a[3] = (__bf16)v0.w;
                a[4] = (__bf16)v1.x; a[5] = (__bf16)v1.y;
                a[6] = (__bf16)v1.z; a[7] = (__bf16)v1.w;
            } else {
                const int mi = (sec == 0) ? 0 : 1;
                a = *(const bf16x8*)(&A[mi][m * KP + koff]);
            }
#pragma unroll
            for (int n = 0; n < 8; n++) {
                const bf16x8 b = *(const bf16x8*)(Wt + (size_t)(n * 16 + m) * K + sec * 128 + koff);
                acc[n] = __builtin_amdgcn_mfma_f32_16x16x32_bf16(a, b, acc[n], 0, 0, 0);
            }
        }
    }

#pragma unroll
    for (int n = 0; n < 8; n++) {
        const int col = n * 16 + m;
        const float bv = bias[col];
#pragma unroll
        for (int r = 0; r < 4; r++) {
            const int orow = t * 16 + g * 4 + r;
            if (orow < Nrows) out[(size_t)orow * DD + col] = acc[n][r] + bv;
        }
    }
}

// ---- exact overflow correction (rare) ----
__global__ __launch_bounds__(128) void ovf_fix(const int* __restrict__ ovfc, const int2* __restrict__ ovf,
                                               const float* __restrict__ x, const int* __restrict__ cnt,
                                               const __bf16* __restrict__ Wt, int K, int sec,
                                               float* __restrict__ out) {
    int m = *ovfc;
    if (m > OVFC) m = OVFC;
    const int n = threadIdx.x;
    for (int i = blockIdx.x; i < m; i += gridDim.x) {
        const int2 p = ovf[i];
        const float sc = 1.0f / fmaxf((float)cnt[p.x], 1.0f);
        float acc = 0.f;
        for (int k = 0; k < DD; k++)
            acc += x[(size_t)p.y * DD + k] * (float)Wt[(size_t)n * K + sec + k];
        atomicAdd(&out[(size_t)p.x * DD + n], acc * sc);
    }
}

extern "C" void kernel_launch(void* const* d_in, const int* in_sizes, int n_in,
                              void* d_out, int out_size, void* d_ws, size_t ws_size,
                              hipStream_t stream) {
    if (n_in != 18) return;

    const float* x_a = (const float*)d_in[0];
    const float* x_b = (const float*)d_in[1];
    const int* e0_src = (const int*)d_in[2];
    const int* e0_dst = (const int*)d_in[3];
    const int* e1_src = (const int*)d_in[4];
    const int* e1_dst = (const int*)d_in[5];
    const int* e2_src = (const int*)d_in[6];
    const int* e2_dst = (const int*)d_in[7];
    const float* Wl0 = (const float*)d_in[8];
    const float* bl0 = (const float*)d_in[9];
    const float* Wr0 = (const float*)d_in[10];
    const float* Wl1 = (const float*)d_in[11];
    const float* bl1 = (const float*)d_in[12];
    const float* Wr1 = (const float*)d_in[13];
    const float* Wl2 = (const float*)d_in[14];
    const float* bl2 = (const float*)d_in[15];
    const float* Wr2 = (const float*)d_in[16];
    const float* rl  = (const float*)d_in[17];

    const int Na = in_sizes[0] / DD;   // 200000
    const int Nb = in_sizes[1] / DD;   // 100000
    const int E0 = in_sizes[2], E1 = in_sizes[4], E2 = in_sizes[6];

    float* out_f = (float*)d_out;
    float* out_a = out_f;
    float* out_b = out_f + (size_t)Na * DD;
    float* rw_out = out_f + (size_t)Na * DD + (size_t)Nb * DD;

    char* base = (char*)d_ws;
    size_t off = 0;
    auto alloc = [&](size_t bytes) { char* r = base + off; off += (bytes + 511) & ~(size_t)511; return r; };
    int* cnt0 = (int*)alloc((size_t)Na * 4);
    int* cnt1 = (int*)alloc((size_t)Nb * 4);
    int* cnt2 = (int*)alloc((size_t)Na * 4);
    int* ovfc = (int*)alloc(512);
    int2* ovf0 = (int2*)alloc(OVFC * 8);
    int2* ovf1 = (int2*)alloc(OVFC * 8);
    int2* ovf2 = (int2*)alloc(OVFC * 8);
    size_t zero_hi = off;
    __bf16* WtA = (__bf16*)alloc(128 * 384 * 2);
    __bf16* Wtb = (__bf16*)alloc(128 * 256 * 2);
    float* ba = (float*)alloc(512);
    float* bb = (float*)alloc(512);
    size_t b0cap = (size_t)Na * CAP02;
    size_t b1cap = (size_t)Nb * CAP1;
    int* bucket0 = (int*)alloc((b0cap > b1cap ? b0cap : b1cap) * 4);
    int* bucket2 = (int*)alloc((size_t)Na * CAP02 * 4);
    int* bucket1 = bucket0;                     // reused after out_b completes
    if (ws_size < off) return;                  // proven adequate (R24-R28 ran)

    hipMemsetAsync(d_ws, 0, zero_hi, stream);
    prep_kernel<<<1, 128, 0, stream>>>(Wl0, bl0, Wr0, Wl1, bl1, Wr1, Wl2, bl2, Wr2, rl,
                                       WtA, Wtb, ba, bb, rw_out);

    const int fb0 = (E0 + 255) / 256, fb1 = (E1 + 255) / 256, fb2 = (E2 + 255) / 256;

    // ---- out_b: relation 1 (a -> b) ----
    fill_bucket<<<fb1, 256, 0, stream>>>(e1_src, e1_dst, E1, Nb, Na, CAP1, cnt1, bucket1, ovfc + 1, ovf1);
    fused_tile<2><<<(Nb + 15) / 16, 64, 0, stream>>>(x_a, nullptr, x_b,
                                                     cnt1, bucket1, CAP1,
                                                     nullptr, nullptr, 0,
                                                     Wtb, bb, out_b, Nb);
    ovf_fix<<<32, 128, 0, stream>>>(ovfc + 1, ovf1, x_a, cnt1, Wtb, 256, 0, out_b);

    // ---- out_a: relations 0 (a->a) + 2 (b->a) ----
    fill_bucket<<<fb0, 256, 0, stream>>>(e0_src, e0_dst, E0, Na, Na, CAP02, cnt0, bucket0, ovfc + 0, ovf0);
    fill_bucket<<<fb2, 256, 0, stream>>>(e2_src, e2_dst, E2, Na, Nb, CAP02, cnt2, bucket2, ovfc + 2, ovf2);
    fused_tile<3><<<(Na + 15) / 16, 64, 0, stream>>>(x_a, x_b, x_a,
                                                     cnt0, bucket0, CAP02,
                                                     cnt2, bucket2, CAP02,
                                                     WtA, ba, out_a, Na);
    ovf_fix<<<32, 128, 0, stream>>>(ovfc + 0, ovf0, x_a, cnt0, WtA, 384, 0, out_a);
    ovf_fix<<<32, 128, 0, stream>>>(ovfc + 2, ovf2, x_b, cnt2, WtA, 384, 256, out_a);
}